// Round 15
// baseline (364.086 us; speedup 1.0000x reference)
//
#include <hip/hip_runtime.h>
#include <hip/hip_bf16.h>

typedef __bf16 bf16x8 __attribute__((ext_vector_type(8)));
typedef __bf16 bf16x4 __attribute__((ext_vector_type(4)));
typedef float  f32x4  __attribute__((ext_vector_type(4)));

#define SWZ(row, byte) ((byte) ^ (((row) & 15) << 4))

// global -> LDS direct copy, 16B per lane, 1KB per wave-instruction.
__device__ __forceinline__ void gload16(const void* g, void* l) {
    __builtin_amdgcn_global_load_lds(
        (const __attribute__((address_space(1))) void*)g,
        (__attribute__((address_space(3))) void*)l, 16, 0, 0);
}

// ---------------------------------------------------------------------------
// hist: dst histogram (starts the CSR critical path immediately)
// ---------------------------------------------------------------------------
__global__ __launch_bounds__(256) void hist_kernel(const int* __restrict__ dst,
                                                   int* __restrict__ degi, int E) {
    int e = blockIdx.x * 256 + threadIdx.x;
    if (e < E) atomicAdd(&degi[dst[e]], 1);
}

// ---------------------------------------------------------------------------
// CSR scan: coalesced local scan + block scan (fill folds the block add).
// ---------------------------------------------------------------------------
__global__ __launch_bounds__(256) void scan_local(const int* __restrict__ degi,
                                                  int* __restrict__ offs,
                                                  int* __restrict__ bsum, int N) {
    __shared__ int sm[256];
    const int t = threadIdx.x;
    int i = blockIdx.x * 256 + t;
    int v = (i < N) ? degi[i] : 0;
    sm[t] = v;
    __syncthreads();
    for (int d = 1; d < 256; d <<= 1) {
        int a = (t >= d) ? sm[t - d] : 0;
        __syncthreads();
        sm[t] += a;
        __syncthreads();
    }
    if (i < N) offs[i] = sm[t] - v;
    if (t == 255) bsum[blockIdx.x] = sm[t];
}

__global__ __launch_bounds__(256) void scan_blocks(const int* __restrict__ bsum,
                                                   int* __restrict__ bofs, int nb) {
    __shared__ int sm[256];
    const int t = threadIdx.x;
    int v = (t < nb) ? bsum[t] : 0;
    sm[t] = v;
    __syncthreads();
    for (int d = 1; d < 256; d <<= 1) {
        int a = (t >= d) ? sm[t - d] : 0;
        __syncthreads();
        sm[t] += a;
        __syncthreads();
    }
    if (t < nb) bofs[t] = sm[t] - v;
}

// ---------------------------------------------------------------------------
// fill_prep: fused  [0,B_FILL): CSR edge-list fill
//                   [B_FILL, +B_NF): nf->bf16
//                   [+B_W): weights->frag order + u->bf16
// ---------------------------------------------------------------------------
__global__ __launch_bounds__(256) void fill_prep(
    const int* __restrict__ dst, const int* __restrict__ offs,
    const int* __restrict__ bofs, int* __restrict__ cursor,
    int* __restrict__ eidx, int E,
    const float* __restrict__ nf, __bf16* __restrict__ nfb, int nElem,
    const float* __restrict__ eW1, const float* __restrict__ eW2,
    const float* __restrict__ nW1, const float* __restrict__ nW2,
    const float* __restrict__ u,
    __bf16* __restrict__ w1e_f, __bf16* __restrict__ w2e_f,
    __bf16* __restrict__ w1n_f, __bf16* __restrict__ w2n_f,
    __bf16* __restrict__ ub,
    int B_FILL, int B_NF)
{
    int b = blockIdx.x;
    if (b < B_FILL) {
        int e = b * 256 + threadIdx.x;
        if (e < E) {
            int d = dst[e];
            int slot = atomicAdd(&cursor[d], 1);
            eidx[offs[d] + bofs[d >> 8] + slot] = e;
        }
    } else if (b < B_FILL + B_NF) {
        int i = ((b - B_FILL) * 256 + threadIdx.x) * 4;
        if (i < nElem) {
            float4 v = *reinterpret_cast<const float4*>(nf + i);
            bf16x4 o;
            o[0] = (__bf16)v.x; o[1] = (__bf16)v.y; o[2] = (__bf16)v.z; o[3] = (__bf16)v.w;
            *reinterpret_cast<bf16x4*>(nfb + i) = o;
        }
    } else {
        int p = (b - B_FILL - B_NF) * 256 + threadIdx.x;
        if (p < 32768) {                       // eW1: K=256,N=128 -> 64 frags
            int i = p & 7, l = (p >> 3) & 63, f = p >> 9;
            int kk = f >> 3, nt = f & 7, lo = l & 15, hi = l >> 4;
            w1e_f[p] = (__bf16)eW1[(kk * 32 + hi * 8 + i) * 128 + nt * 16 + lo];
        } else if (p < 40960) {                // eW2: K=128,N=64 -> 16 frags
            int j = p - 32768;
            int i = j & 7, l = (j >> 3) & 63, g = j >> 9;
            int kk = g >> 2, nt = g & 3, lo = l & 15, hi = l >> 4;
            w2e_f[j] = (__bf16)eW2[(kk * 32 + hi * 8 + i) * 64 + nt * 16 + lo];
        } else if (p < 65536) {                // nW1: K=192,N=128 -> 48 frags
            int j = p - 40960;
            int i = j & 7, l = (j >> 3) & 63, f = j >> 9;
            int kk = f >> 3, nt = f & 7, lo = l & 15, hi = l >> 4;
            w1n_f[j] = (__bf16)nW1[(kk * 32 + hi * 8 + i) * 128 + nt * 16 + lo];
        } else if (p < 73728) {                // nW2: K=128,N=64 -> 16 frags
            int j = p - 65536;
            int i = j & 7, l = (j >> 3) & 63, g = j >> 9;
            int kk = g >> 2, nt = g & 3, lo = l & 15, hi = l >> 4;
            w2n_f[j] = (__bf16)nW2[(kk * 32 + hi * 8 + i) * 64 + nt * 16 + lo];
        } else if (p < 73792) {
            ub[p - 73728] = (__bf16)u[p - 73728];
        }
    }
}

// ---------------------------------------------------------------------------
// Edge MLP, MFMA, CSR-ordered + fused segmented aggregation.
// 1024 threads = 16 waves x 16 CSR slots = 256 edges/block.
// LDS 80KB = [0,64K) W1 (staged once, h overlays it after barrier 2)
//          | [64K,80K) W2.  2 blocks/CU = 160KiB exactly; VGPR <= 64 target
// gives 32 waves/CU (vs 16 before) -> latency hiding doubles.
// ---------------------------------------------------------------------------
__global__ __launch_bounds__(1024, 4) void edge_mfma(
    const float* __restrict__ ef,
    const __bf16* __restrict__ nfb, const __bf16* __restrict__ ub,
    const bf16x8* __restrict__ w1f, const bf16x8* __restrict__ w2f,
    const float* __restrict__ b1, const float* __restrict__ b2,
    const int* __restrict__ src, const int* __restrict__ dst,
    const int* __restrict__ eidx,
    float* __restrict__ out_e, float* __restrict__ agg,
    int E)
{
    __shared__ alignas(16) char lds[81920];
    const int tid = threadIdx.x;
    const int w = tid >> 6, l = tid & 63;
    const int lo = l & 15, hi = l >> 4;
    const long wb = (long)blockIdx.x * 256 + w * 16;   // CSR slot base of wave

    long jL = wb + lo;
    const bool vL = (jL < E);
    const int eA = vL ? eidx[jL] : 0;
    const int srcA = src[eA];
    const int dstA = vL ? dst[eA] : -1;     // -1 isolates invalid rows

    // ---- issue all A-fragment gathers up-front
    bf16x8 afr[8];
#pragma unroll
    for (int kk = 0; kk < 8; ++kk) {
        const int koff = (kk & 1) * 32 + hi * 8;
        const int sec = kk >> 1;
        if (sec == 0) {
            afr[kk] = *(const bf16x8*)(nfb + (size_t)srcA * 64 + koff);
        } else if (sec == 1) {
            int dg = (dstA >= 0) ? dstA : 0;
            afr[kk] = *(const bf16x8*)(nfb + (size_t)dg * 64 + koff);
        } else if (sec == 2) {
            const float* p = ef + (size_t)eA * 64 + koff;
            float4 v0 = *(const float4*)p;
            float4 v1 = *(const float4*)(p + 4);
            bf16x8 t;
            t[0] = (__bf16)v0.x; t[1] = (__bf16)v0.y; t[2] = (__bf16)v0.z; t[3] = (__bf16)v0.w;
            t[4] = (__bf16)v1.x; t[5] = (__bf16)v1.y; t[6] = (__bf16)v1.z; t[7] = (__bf16)v1.w;
            afr[kk] = t;
        } else {
            afr[kk] = *(const bf16x8*)(ub + koff);
        }
    }

    // ---- preload residual ef rows (L1/L2-hot from the fragment reads)
    int erA[4];
#pragma unroll
    for (int r = 0; r < 4; ++r)
        erA[r] = __shfl(eA, hi * 4 + r);
    float resv[4][4];
#pragma unroll
    for (int r = 0; r < 4; ++r)
#pragma unroll
        for (int nt = 0; nt < 4; ++nt)
            resv[r][nt] = ef[(size_t)erA[r] * 64 + nt * 16 + lo];

    float b1v[8];
#pragma unroll
    for (int nt = 0; nt < 8; ++nt) b1v[nt] = b1[nt * 16 + lo];
    float b2v[4];
#pragma unroll
    for (int nt = 0; nt < 4; ++nt) b2v[nt] = b2[nt * 16 + lo];

    // ---- stage ALL weights once: W1 (64 chunks) + W2 (16 chunks), 16 waves
    for (int c = w; c < 64; c += 16)
        gload16(w1f + c * 64 + l, lds + c * 1024);
    if (w < 16) {
        int c = w;
        gload16(w2f + c * 64 + l, lds + 65536 + c * 1024);
    }
    __syncthreads();   // barrier 1: weights staged

    // ---- layer 1: all 8 kk
    f32x4 acc1[8] = {};
#pragma unroll
    for (int kk = 0; kk < 8; ++kk)
#pragma unroll
        for (int nt = 0; nt < 8; ++nt) {
            bf16x8 bfr = *(const bf16x8*)(lds + ((kk * 8 + nt) * 64 + l) * 16);
            acc1[nt] = __builtin_amdgcn_mfma_f32_16x16x32_bf16(afr[kk], bfr, acc1[nt], 0, 0, 0);
        }
    __syncthreads();   // barrier 2: all W1 reads done; [0,64K) reusable for h

    // ---- h = relu(acc1+b1) -> per-wave 4KB region (16 waves x 4KB = 64KB)
    char* hp = lds + w * 4096;
#pragma unroll
    for (int nt = 0; nt < 8; ++nt) {
        int col = nt * 16 + lo;
#pragma unroll
        for (int r = 0; r < 4; ++r) {
            int row = hi * 4 + r;
            float hv = fmaxf(acc1[nt][r] + b1v[nt], 0.0f);
            *(__bf16*)(hp + SWZ(row, row * 256 + col * 2)) = (__bf16)hv;
        }
    }

    // ---- layer 2
    f32x4 acc2[4] = {};
#pragma unroll
    for (int kk = 0; kk < 4; ++kk) {
        int kb = (kk * 32 + hi * 8) * 2;
        bf16x8 a0 = *(const bf16x8*)(hp + SWZ(lo, lo * 256 + kb));
#pragma unroll
        for (int nt = 0; nt < 4; ++nt) {
            bf16x8 bfr = *(const bf16x8*)(lds + 65536 + ((kk * 4 + nt) * 64 + l) * 16);
            acc2[nt] = __builtin_amdgcn_mfma_f32_16x16x32_bf16(a0, bfr, acc2[nt], 0, 0, 0);
        }
    }

    // ---- fold bias once: acc2 = msg
#pragma unroll
    for (int nt = 0; nt < 4; ++nt)
#pragma unroll
        for (int r = 0; r < 4; ++r)
            acc2[nt][r] += b2v[nt];

    // ---- epilogue A: residual store (registers only)
#pragma unroll
    for (int r = 0; r < 4; ++r) {
        int row = hi * 4 + r;
        if (wb + row >= E) continue;
#pragma unroll
        for (int nt = 0; nt < 4; ++nt)
            out_e[(size_t)erA[r] * 64 + nt * 16 + lo] = acc2[nt][r] + resv[r][nt];
    }

    // ---- epilogue B: dst-segmented reduction -> f32 atomics into agg
    int dn = __shfl(dstA, (l + 1) & 63);
    unsigned long long bal = __ballot(dstA != dn);
    unsigned mm = ((unsigned)bal & 0x7FFFu) | 0x8000u;   // row15 always ends a segment
    int startRow = 0;
    while (mm) {
        int endRow = __ffs(mm);              // segment rows [startRow, endRow)
        int d = __shfl(dstA, startRow);      // uniform
        if (d >= 0) {
            float s0 = 0.f, s1 = 0.f, s2 = 0.f, s3 = 0.f;
#pragma unroll
            for (int r = 0; r < 4; ++r) {
                int row = hi * 4 + r;
                if (row >= startRow && row < endRow) {
                    s0 += acc2[0][r];
                    s1 += acc2[1][r];
                    s2 += acc2[2][r];
                    s3 += acc2[3][r];
                }
            }
            s0 += __shfl_xor(s0, 16); s0 += __shfl_xor(s0, 32);
            s1 += __shfl_xor(s1, 16); s1 += __shfl_xor(s1, 32);
            s2 += __shfl_xor(s2, 16); s2 += __shfl_xor(s2, 32);
            s3 += __shfl_xor(s3, 16); s3 += __shfl_xor(s3, 32);
            if (l < 16) {
                float* ap = agg + (size_t)d * 64;
                atomicAdd(ap + l,      s0);
                atomicAdd(ap + 16 + l, s1);
                atomicAdd(ap + 32 + l, s2);
                atomicAdd(ap + 48 + l, s3);
            }
        }
        startRow = endRow;
        mm &= mm - 1;
    }
}

// ---------------------------------------------------------------------------
// Node MLP, MFMA. K=192 (agg/deg | nfb | u). 1024 threads = 16 waves,
// 256 nodes/block. LDS 80KB: [0,48K) W1n | [64K,80K) W2; h (16x4KB=64KB)
// overlays [0,64K) after the W1 barrier.
// ---------------------------------------------------------------------------
__global__ __launch_bounds__(1024, 4) void node_mfma(
    const float* __restrict__ nf,
    const __bf16* __restrict__ nfb, const __bf16* __restrict__ ub,
    const float* __restrict__ agg, const int* __restrict__ degi,
    const bf16x8* __restrict__ w1f, const bf16x8* __restrict__ w2f,
    const float* __restrict__ b1, const float* __restrict__ b2,
    float* __restrict__ out_n, float* __restrict__ nsum_part,
    int N)
{
    __shared__ alignas(16) char lds[81920];
    const int tid = threadIdx.x;
    const int w = tid >> 6, l = tid & 63;
    const int lo = l & 15, hi = l >> 4;
    const long nb = (long)blockIdx.x * 256 + w * 16;

    long gnL = nb + lo;
    const int gnA = (gnL < N) ? (int)gnL : 0;
    const float inv = 1.0f / fmaxf((float)degi[gnA], 1.0f);

    bf16x8 afr[6];
#pragma unroll
    for (int kk = 0; kk < 6; ++kk) {
        const int koff = (kk & 1) * 32 + hi * 8;
        const int sec = kk >> 1;
        if (sec == 0) {
            const float* p = agg + (size_t)gnA * 64 + koff;
            float4 v0 = *(const float4*)p;
            float4 v1 = *(const float4*)(p + 4);
            bf16x8 t;
            t[0] = (__bf16)(v0.x * inv); t[1] = (__bf16)(v0.y * inv);
            t[2] = (__bf16)(v0.z * inv); t[3] = (__bf16)(v0.w * inv);
            t[4] = (__bf16)(v1.x * inv); t[5] = (__bf16)(v1.y * inv);
            t[6] = (__bf16)(v1.z * inv); t[7] = (__bf16)(v1.w * inv);
            afr[kk] = t;
        } else if (sec == 1) {
            afr[kk] = *(const bf16x8*)(nfb + (size_t)gnA * 64 + koff);
        } else {
            afr[kk] = *(const bf16x8*)(ub + koff);
        }
    }

    float b1v[8];
#pragma unroll
    for (int nt = 0; nt < 8; ++nt) b1v[nt] = b1[nt * 16 + lo];
    float b2v[4];
#pragma unroll
    for (int nt = 0; nt < 4; ++nt) b2v[nt] = b2[nt * 16 + lo];

    // ---- stage W1n (48 chunks) + W2 (16 chunks), once, 16 waves
    for (int c = w; c < 48; c += 16)
        gload16(w1f + c * 64 + l, lds + c * 1024);
    if (w < 16) {
        int c = w;
        gload16(w2f + c * 64 + l, lds + 65536 + c * 1024);
    }
    __syncthreads();

    // ---- layer 1: kk = 0..5
    f32x4 acc1[8] = {};
#pragma unroll
    for (int kk = 0; kk < 6; ++kk)
#pragma unroll
        for (int nt = 0; nt < 8; ++nt) {
            bf16x8 bfr = *(const bf16x8*)(lds + ((kk * 8 + nt) * 64 + l) * 16);
            acc1[nt] = __builtin_amdgcn_mfma_f32_16x16x32_bf16(afr[kk], bfr, acc1[nt], 0, 0, 0);
        }
    __syncthreads();   // all W1 reads done; [0,64K) reusable for h

    char* hp = lds + w * 4096;
#pragma unroll
    for (int nt = 0; nt < 8; ++nt) {
        int col = nt * 16 + lo;
#pragma unroll
        for (int r = 0; r < 4; ++r) {
            int row = hi * 4 + r;
            float hv = fmaxf(acc1[nt][r] + b1v[nt], 0.0f);
            *(__bf16*)(hp + SWZ(row, row * 256 + col * 2)) = (__bf16)hv;
        }
    }

    f32x4 acc2[4] = {};
#pragma unroll
    for (int kk = 0; kk < 4; ++kk) {
        int kb = (kk * 32 + hi * 8) * 2;
        bf16x8 a0 = *(const bf16x8*)(hp + SWZ(lo, lo * 256 + kb));
#pragma unroll
        for (int nt = 0; nt < 4; ++nt) {
            bf16x8 bfr = *(const bf16x8*)(lds + 65536 + ((kk * 4 + nt) * 64 + l) * 16);
            acc2[nt] = __builtin_amdgcn_mfma_f32_16x16x32_bf16(a0, bfr, acc2[nt], 0, 0, 0);
        }
    }

    float vsum[4] = {0.f, 0.f, 0.f, 0.f};
#pragma unroll
    for (int r = 0; r < 4; ++r) {
        long gn = nb + hi * 4 + r;
        if (gn >= N) continue;
        int gni = (int)gn;
#pragma unroll
        for (int nt = 0; nt < 4; ++nt) {
            int col = nt * 16 + lo;
            float msg = acc2[nt][r] + b2v[nt];
            out_n[(size_t)gni * 64 + col] = msg + nf[(size_t)gni * 64 + col];
            vsum[nt] += msg;
        }
    }
#pragma unroll
    for (int nt = 0; nt < 4; ++nt) {
        float v = vsum[nt];
        v += __shfl_xor(v, 16);
        v += __shfl_xor(v, 32);
        if (l < 16) nsum_part[((size_t)blockIdx.x * 16 + w) * 64 + nt * 16 + l] = v;
    }
}

// ---------------------------------------------------------------------------
// reduce_two: blocks [0,NBA) sum agg rows -> edge_sum;
//             blocks [NBA,NBA+NBB) sum nsum_part rows -> node_sum.
// ---------------------------------------------------------------------------
__global__ __launch_bounds__(256) void reduce_two(
    const float* __restrict__ aggIn, float* __restrict__ edge_sum, int RA, int NBA,
    const float* __restrict__ nsumIn, float* __restrict__ node_sum, int RB, int NBB)
{
    const float* in; float* out; int R, rb, nb;
    if ((int)blockIdx.x < NBA) { in = aggIn;  out = edge_sum; R = RA; rb = blockIdx.x;       nb = NBA; }
    else                       { in = nsumIn; out = node_sum; R = RB; rb = blockIdx.x - NBA; nb = NBB; }
    int col = threadIdx.x & 63;
    float s = 0.f;
    for (int r = rb * 4 + (threadIdx.x >> 6); r < R; r += nb * 4)
        s += in[(size_t)r * 64 + col];
    __shared__ float sm[256];
    sm[threadIdx.x] = s;
    __syncthreads();
    if (threadIdx.x < 64) {
        float v = sm[threadIdx.x] + sm[threadIdx.x + 64] + sm[threadIdx.x + 128] + sm[threadIdx.x + 192];
        atomicAdd(&out[threadIdx.x], v);
    }
}

// ---------------------------------------------------------------------------
// Global MLP: single block.
// ---------------------------------------------------------------------------
__global__ __launch_bounds__(128) void global_kernel(
    const float* __restrict__ u,
    const float* __restrict__ W1, const float* __restrict__ b1,
    const float* __restrict__ W2, const float* __restrict__ b2,
    const float* __restrict__ node_sum, const float* __restrict__ edge_sum,
    float* __restrict__ out_u, int N, int E)
{
    __shared__ float gm[192];
    __shared__ float h[128];
    int tid = threadIdx.x;
    if (tid < 64) {
        gm[tid]       = node_sum[tid] / (float)N;
        gm[64 + tid]  = edge_sum[tid] / (float)E;
        gm[128 + tid] = u[tid];
    }
    __syncthreads();
    float a = b1[tid];
    for (int k = 0; k < 192; ++k) a = fmaf(gm[k], W1[k * 128 + tid], a);
    h[tid] = fmaxf(a, 0.f);
    __syncthreads();
    if (tid < 64) {
        float o = b2[tid];
        for (int k = 0; k < 128; ++k) o = fmaf(h[k], W2[k * 64 + tid], o);
        out_u[tid] = o + u[tid];
    }
}

extern "C" void kernel_launch(void* const* d_in, const int* in_sizes, int n_in,
                              void* d_out, int out_size, void* d_ws, size_t ws_size,
                              hipStream_t stream) {
    const float* nf  = (const float*)d_in[0];
    const float* ef  = (const float*)d_in[1];
    const float* u   = (const float*)d_in[2];
    const float* eW1 = (const float*)d_in[3];
    const float* eb1 = (const float*)d_in[4];
    const float* eW2 = (const float*)d_in[5];
    const float* eb2 = (const float*)d_in[6];
    const float* nW1 = (const float*)d_in[7];
    const float* nb1 = (const float*)d_in[8];
    const float* nW2 = (const float*)d_in[9];
    const float* nb2 = (const float*)d_in[10];
    const float* gW1 = (const float*)d_in[11];
    const float* gb1 = (const float*)d_in[12];
    const float* gW2 = (const float*)d_in[13];
    const float* gb2 = (const float*)d_in[14];
    const int*   src = (const int*)d_in[15];
    const int*   dst = (const int*)d_in[16];

    const int N = in_sizes[0] / 64;
    const int E = in_sizes[1] / 64;
    const int EDGE_BLOCKS = (E + 255) / 256;
    const int NODE_BLOCKS = (N + 255) / 256;
    const int SCAN_NB = (N + 255) / 256;       // <= 256 for N <= 65536

    char* ws = (char*)d_ws;
    size_t off_b = 0;
    auto alloc = [&](size_t bytes) { size_t c = off_b; off_b += (bytes + 255) & ~(size_t)255; return c; };

    // zeroed region first: degi | cursor | edge_sum | node_sum | agg
    int*    degi     = (int*)(ws + alloc((size_t)N * 4));
    int*    cursor   = (int*)(ws + alloc((size_t)N * 4));
    float*  edge_sum = (float*)(ws + alloc(256));
    float*  node_sum = (float*)(ws + alloc(256));
    float*  agg      = (float*)(ws + alloc((size_t)N * 64 * 4));
    size_t  zero_bytes = off_b;
    int*    offs     = (int*)(ws + alloc((size_t)N * 4));
    int*    bsum     = (int*)(ws + alloc((size_t)SCAN_NB * 4));
    int*    bofs     = (int*)(ws + alloc((size_t)SCAN_NB * 4));
    int*    eidx     = (int*)(ws + alloc((size_t)E * 4));
    float*  nsum_part= (float*)(ws + alloc((size_t)NODE_BLOCKS * 16 * 64 * 4));
    __bf16* nfb   = (__bf16*)(ws + alloc((size_t)N * 64 * 2));
    __bf16* ub    = (__bf16*)(ws + alloc(256));
    __bf16* w1e_f = (__bf16*)(ws + alloc(32768 * 2));
    __bf16* w2e_f = (__bf16*)(ws + alloc(8192 * 2));
    __bf16* w1n_f = (__bf16*)(ws + alloc(24576 * 2));
    __bf16* w2n_f = (__bf16*)(ws + alloc(8192 * 2));

    float* out_n = (float*)d_out;
    float* out_e = out_n + (size_t)N * 64;
    float* out_u = out_e + (size_t)E * 64;

    const int B_FILL = (E + 255) / 256;
    const int B_NF   = (N * 16 + 255) / 256;   // N*64/4 threads
    const int B_W    = (73792 + 255) / 256;

    hipMemsetAsync(d_ws, 0, zero_bytes, stream);
    hist_kernel<<<(E + 255) / 256, 256, 0, stream>>>(dst, degi, E);
    scan_local<<<SCAN_NB, 256, 0, stream>>>(degi, offs, bsum, N);
    scan_blocks<<<1, 256, 0, stream>>>(bsum, bofs, SCAN_NB);
    fill_prep<<<B_FILL + B_NF + B_W, 256, 0, stream>>>(
        dst, offs, bofs, cursor, eidx, E,
        nf, nfb, N * 64, eW1, eW2, nW1, nW2, u,
        w1e_f, w2e_f, w1n_f, w2n_f, ub, B_FILL, B_NF);
    edge_mfma<<<EDGE_BLOCKS, 1024, 0, stream>>>(
        ef, nfb, ub, (const bf16x8*)w1e_f, (const bf16x8*)w2e_f, eb1, eb2,
        src, dst, eidx, out_e, agg, E);
    node_mfma<<<NODE_BLOCKS, 1024, 0, stream>>>(
        nf, nfb, ub, agg, degi, (const bf16x8*)w1n_f, (const bf16x8*)w2n_f,
        nb1, nb2, out_n, nsum_part, N);
    reduce_two<<<128 + 16, 256, 0, stream>>>(
        agg, edge_sum, N, 128, nsum_part, node_sum, NODE_BLOCKS * 16, 16);
    global_kernel<<<1, 128, 0, stream>>>(
        u, gW1, gb1, gW2, gb2, node_sum, edge_sum, out_u, N, E);
}

// Round 16
// 329.699 us; speedup vs baseline: 1.1043x; 1.1043x over previous
//
#include <hip/hip_runtime.h>
#include <hip/hip_bf16.h>

typedef __bf16 bf16x8 __attribute__((ext_vector_type(8)));
typedef __bf16 bf16x4 __attribute__((ext_vector_type(4)));
typedef float  f32x4  __attribute__((ext_vector_type(4)));

#define SWZ(row, byte) ((byte) ^ (((row) & 15) << 4))

// global -> LDS direct copy, 16B per lane, 1KB per wave-instruction.
__device__ __forceinline__ void gload16(const void* g, void* l) {
    __builtin_amdgcn_global_load_lds(
        (const __attribute__((address_space(1))) void*)g,
        (__attribute__((address_space(3))) void*)l, 16, 0, 0);
}

// ---------------------------------------------------------------------------
// hist: dst histogram (starts the CSR critical path immediately)
// ---------------------------------------------------------------------------
__global__ __launch_bounds__(256) void hist_kernel(const int* __restrict__ dst,
                                                   int* __restrict__ degi, int E) {
    int e = blockIdx.x * 256 + threadIdx.x;
    if (e < E) atomicAdd(&degi[dst[e]], 1);
}

// ---------------------------------------------------------------------------
// CSR scan: coalesced local scan + block scan (fill folds the block add).
// ---------------------------------------------------------------------------
__global__ __launch_bounds__(256) void scan_local(const int* __restrict__ degi,
                                                  int* __restrict__ offs,
                                                  int* __restrict__ bsum, int N) {
    __shared__ int sm[256];
    const int t = threadIdx.x;
    int i = blockIdx.x * 256 + t;
    int v = (i < N) ? degi[i] : 0;
    sm[t] = v;
    __syncthreads();
    for (int d = 1; d < 256; d <<= 1) {
        int a = (t >= d) ? sm[t - d] : 0;
        __syncthreads();
        sm[t] += a;
        __syncthreads();
    }
    if (i < N) offs[i] = sm[t] - v;
    if (t == 255) bsum[blockIdx.x] = sm[t];
}

__global__ __launch_bounds__(256) void scan_blocks(const int* __restrict__ bsum,
                                                   int* __restrict__ bofs, int nb) {
    __shared__ int sm[256];
    const int t = threadIdx.x;
    int v = (t < nb) ? bsum[t] : 0;
    sm[t] = v;
    __syncthreads();
    for (int d = 1; d < 256; d <<= 1) {
        int a = (t >= d) ? sm[t - d] : 0;
        __syncthreads();
        sm[t] += a;
        __syncthreads();
    }
    if (t < nb) bofs[t] = sm[t] - v;
}

// ---------------------------------------------------------------------------
// fill_prep: fused  [0,B_FILL): CSR edge-list fill
//                   [B_FILL, +B_NF): nf->bf16
//                   [+B_W): weights->frag order + u->bf16
// ---------------------------------------------------------------------------
__global__ __launch_bounds__(256) void fill_prep(
    const int* __restrict__ dst, const int* __restrict__ offs,
    const int* __restrict__ bofs, int* __restrict__ cursor,
    int* __restrict__ eidx, int E,
    const float* __restrict__ nf, __bf16* __restrict__ nfb, int nElem,
    const float* __restrict__ eW1, const float* __restrict__ eW2,
    const float* __restrict__ nW1, const float* __restrict__ nW2,
    const float* __restrict__ u,
    __bf16* __restrict__ w1e_f, __bf16* __restrict__ w2e_f,
    __bf16* __restrict__ w1n_f, __bf16* __restrict__ w2n_f,
    __bf16* __restrict__ ub,
    int B_FILL, int B_NF)
{
    int b = blockIdx.x;
    if (b < B_FILL) {
        int e = b * 256 + threadIdx.x;
        if (e < E) {
            int d = dst[e];
            int slot = atomicAdd(&cursor[d], 1);
            eidx[offs[d] + bofs[d >> 8] + slot] = e;
        }
    } else if (b < B_FILL + B_NF) {
        int i = ((b - B_FILL) * 256 + threadIdx.x) * 4;
        if (i < nElem) {
            float4 v = *reinterpret_cast<const float4*>(nf + i);
            bf16x4 o;
            o[0] = (__bf16)v.x; o[1] = (__bf16)v.y; o[2] = (__bf16)v.z; o[3] = (__bf16)v.w;
            *reinterpret_cast<bf16x4*>(nfb + i) = o;
        }
    } else {
        int p = (b - B_FILL - B_NF) * 256 + threadIdx.x;
        if (p < 32768) {                       // eW1: K=256,N=128 -> 64 frags
            int i = p & 7, l = (p >> 3) & 63, f = p >> 9;
            int kk = f >> 3, nt = f & 7, lo = l & 15, hi = l >> 4;
            w1e_f[p] = (__bf16)eW1[(kk * 32 + hi * 8 + i) * 128 + nt * 16 + lo];
        } else if (p < 40960) {                // eW2: K=128,N=64 -> 16 frags
            int j = p - 32768;
            int i = j & 7, l = (j >> 3) & 63, g = j >> 9;
            int kk = g >> 2, nt = g & 3, lo = l & 15, hi = l >> 4;
            w2e_f[j] = (__bf16)eW2[(kk * 32 + hi * 8 + i) * 64 + nt * 16 + lo];
        } else if (p < 65536) {                // nW1: K=192,N=128 -> 48 frags
            int j = p - 40960;
            int i = j & 7, l = (j >> 3) & 63, f = j >> 9;
            int kk = f >> 3, nt = f & 7, lo = l & 15, hi = l >> 4;
            w1n_f[j] = (__bf16)nW1[(kk * 32 + hi * 8 + i) * 128 + nt * 16 + lo];
        } else if (p < 73728) {                // nW2: K=128,N=64 -> 16 frags
            int j = p - 65536;
            int i = j & 7, l = (j >> 3) & 63, g = j >> 9;
            int kk = g >> 2, nt = g & 3, lo = l & 15, hi = l >> 4;
            w2n_f[j] = (__bf16)nW2[(kk * 32 + hi * 8 + i) * 64 + nt * 16 + lo];
        } else if (p < 73792) {
            ub[p - 73728] = (__bf16)u[p - 73728];
        }
    }
}

// ---------------------------------------------------------------------------
// Edge MLP, MFMA, CSR-ordered + fused segmented aggregation.
// 512 threads = 8 waves x 16 CSR slots = 128 edges/block.
// SINGLE-STAGE: LDS 80KB = [0,64K) all of W1 + [64K,80K) W2, staged once via
// global_load_lds; 2 barriers per block. Verified best structure (R14).
// ---------------------------------------------------------------------------
__global__ __launch_bounds__(512, 4) void edge_mfma(
    const float* __restrict__ ef,
    const __bf16* __restrict__ nfb, const __bf16* __restrict__ ub,
    const bf16x8* __restrict__ w1f, const bf16x8* __restrict__ w2f,
    const float* __restrict__ b1, const float* __restrict__ b2,
    const int* __restrict__ src, const int* __restrict__ dst,
    const int* __restrict__ eidx,
    float* __restrict__ out_e, float* __restrict__ agg,
    int E)
{
    __shared__ alignas(16) char lds[81920];
    const int tid = threadIdx.x;
    const int w = tid >> 6, l = tid & 63;
    const int lo = l & 15, hi = l >> 4;
    const long wb = (long)blockIdx.x * 128 + w * 16;   // CSR slot base of wave

    long jL = wb + lo;
    const bool vL = (jL < E);
    const int eA = vL ? eidx[jL] : 0;
    const int srcA = src[eA];
    const int dstA = vL ? dst[eA] : -1;     // -1 isolates invalid rows

    // ---- issue all A-fragment gathers up-front
    bf16x8 afr[8];
#pragma unroll
    for (int kk = 0; kk < 8; ++kk) {
        const int koff = (kk & 1) * 32 + hi * 8;
        const int sec = kk >> 1;
        if (sec == 0) {
            afr[kk] = *(const bf16x8*)(nfb + (size_t)srcA * 64 + koff);
        } else if (sec == 1) {
            int dg = (dstA >= 0) ? dstA : 0;
            afr[kk] = *(const bf16x8*)(nfb + (size_t)dg * 64 + koff);
        } else if (sec == 2) {
            const float* p = ef + (size_t)eA * 64 + koff;
            float4 v0 = *(const float4*)p;
            float4 v1 = *(const float4*)(p + 4);
            bf16x8 t;
            t[0] = (__bf16)v0.x; t[1] = (__bf16)v0.y; t[2] = (__bf16)v0.z; t[3] = (__bf16)v0.w;
            t[4] = (__bf16)v1.x; t[5] = (__bf16)v1.y; t[6] = (__bf16)v1.z; t[7] = (__bf16)v1.w;
            afr[kk] = t;
        } else {
            afr[kk] = *(const bf16x8*)(ub + koff);
        }
    }

    // ---- preload residual ef rows (L1/L2-hot from the fragment reads)
    int erA[4];
#pragma unroll
    for (int r = 0; r < 4; ++r)
        erA[r] = __shfl(eA, hi * 4 + r);
    float resv[4][4];
#pragma unroll
    for (int r = 0; r < 4; ++r)
#pragma unroll
        for (int nt = 0; nt < 4; ++nt)
            resv[r][nt] = ef[(size_t)erA[r] * 64 + nt * 16 + lo];

    float b1v[8];
#pragma unroll
    for (int nt = 0; nt < 8; ++nt) b1v[nt] = b1[nt * 16 + lo];
    float b2v[4];
#pragma unroll
    for (int nt = 0; nt < 4; ++nt) b2v[nt] = b2[nt * 16 + lo];

    // ---- stage ALL weights once: W1 (64 chunks) + W2 (16 chunks)
    for (int c = w; c < 64; c += 8)
        gload16(w1f + c * 64 + l, lds + c * 1024);
    for (int c = w; c < 16; c += 8)
        gload16(w2f + c * 64 + l, lds + 65536 + c * 1024);
    __syncthreads();   // barrier 1: weights staged

    // ---- layer 1: all 8 kk
    f32x4 acc1[8] = {};
#pragma unroll
    for (int kk = 0; kk < 8; ++kk)
#pragma unroll
        for (int nt = 0; nt < 8; ++nt) {
            bf16x8 bfr = *(const bf16x8*)(lds + ((kk * 8 + nt) * 64 + l) * 16);
            acc1[nt] = __builtin_amdgcn_mfma_f32_16x16x32_bf16(afr[kk], bfr, acc1[nt], 0, 0, 0);
        }
    __syncthreads();   // barrier 2: all W1 reads done; [0,32K) reusable for h

    // ---- h = relu(acc1+b1) -> per-wave 4KB region
    char* hp = lds + w * 4096;
#pragma unroll
    for (int nt = 0; nt < 8; ++nt) {
        int col = nt * 16 + lo;
#pragma unroll
        for (int r = 0; r < 4; ++r) {
            int row = hi * 4 + r;
            float hv = fmaxf(acc1[nt][r] + b1v[nt], 0.0f);
            *(__bf16*)(hp + SWZ(row, row * 256 + col * 2)) = (__bf16)hv;
        }
    }

    // ---- layer 2
    f32x4 acc2[4] = {};
#pragma unroll
    for (int kk = 0; kk < 4; ++kk) {
        int kb = (kk * 32 + hi * 8) * 2;
        bf16x8 a0 = *(const bf16x8*)(hp + SWZ(lo, lo * 256 + kb));
#pragma unroll
        for (int nt = 0; nt < 4; ++nt) {
            bf16x8 bfr = *(const bf16x8*)(lds + 65536 + ((kk * 4 + nt) * 64 + l) * 16);
            acc2[nt] = __builtin_amdgcn_mfma_f32_16x16x32_bf16(a0, bfr, acc2[nt], 0, 0, 0);
        }
    }

    // ---- fold bias once: acc2 = msg
#pragma unroll
    for (int nt = 0; nt < 4; ++nt)
#pragma unroll
        for (int r = 0; r < 4; ++r)
            acc2[nt][r] += b2v[nt];

    // ---- epilogue A: residual store (registers only)
#pragma unroll
    for (int r = 0; r < 4; ++r) {
        int row = hi * 4 + r;
        if (wb + row >= E) continue;
#pragma unroll
        for (int nt = 0; nt < 4; ++nt)
            out_e[(size_t)erA[r] * 64 + nt * 16 + lo] = acc2[nt][r] + resv[r][nt];
    }

    // ---- epilogue B: dst-segmented reduction -> f32 atomics into agg
    int dn = __shfl(dstA, (l + 1) & 63);
    unsigned long long bal = __ballot(dstA != dn);
    unsigned mm = ((unsigned)bal & 0x7FFFu) | 0x8000u;   // row15 always ends a segment
    int startRow = 0;
    while (mm) {
        int endRow = __ffs(mm);              // segment rows [startRow, endRow)
        int d = __shfl(dstA, startRow);      // uniform
        if (d >= 0) {
            float s0 = 0.f, s1 = 0.f, s2 = 0.f, s3 = 0.f;
#pragma unroll
            for (int r = 0; r < 4; ++r) {
                int row = hi * 4 + r;
                if (row >= startRow && row < endRow) {
                    s0 += acc2[0][r];
                    s1 += acc2[1][r];
                    s2 += acc2[2][r];
                    s3 += acc2[3][r];
                }
            }
            s0 += __shfl_xor(s0, 16); s0 += __shfl_xor(s0, 32);
            s1 += __shfl_xor(s1, 16); s1 += __shfl_xor(s1, 32);
            s2 += __shfl_xor(s2, 16); s2 += __shfl_xor(s2, 32);
            s3 += __shfl_xor(s3, 16); s3 += __shfl_xor(s3, 32);
            if (l < 16) {
                float* ap = agg + (size_t)d * 64;
                atomicAdd(ap + l,      s0);
                atomicAdd(ap + 16 + l, s1);
                atomicAdd(ap + 32 + l, s2);
                atomicAdd(ap + 48 + l, s3);
            }
        }
        startRow = endRow;
        mm &= mm - 1;
    }
}

// ---------------------------------------------------------------------------
// Node MLP, MFMA. K=192 (agg/deg | nfb | u). Single-stage 64KB LDS.
// ---------------------------------------------------------------------------
__global__ __launch_bounds__(512, 4) void node_mfma(
    const float* __restrict__ nf,
    const __bf16* __restrict__ nfb, const __bf16* __restrict__ ub,
    const float* __restrict__ agg, const int* __restrict__ degi,
    const bf16x8* __restrict__ w1f, const bf16x8* __restrict__ w2f,
    const float* __restrict__ b1, const float* __restrict__ b2,
    float* __restrict__ out_n, float* __restrict__ nsum_part,
    int N)
{
    __shared__ alignas(16) char lds[65536];
    const int tid = threadIdx.x;
    const int w = tid >> 6, l = tid & 63;
    const int lo = l & 15, hi = l >> 4;
    const long nb = (long)blockIdx.x * 128 + w * 16;

    long gnL = nb + lo;
    const int gnA = (gnL < N) ? (int)gnL : 0;
    const float inv = 1.0f / fmaxf((float)degi[gnA], 1.0f);

    bf16x8 afr[6];
#pragma unroll
    for (int kk = 0; kk < 6; ++kk) {
        const int koff = (kk & 1) * 32 + hi * 8;
        const int sec = kk >> 1;
        if (sec == 0) {
            const float* p = agg + (size_t)gnA * 64 + koff;
            float4 v0 = *(const float4*)p;
            float4 v1 = *(const float4*)(p + 4);
            bf16x8 t;
            t[0] = (__bf16)(v0.x * inv); t[1] = (__bf16)(v0.y * inv);
            t[2] = (__bf16)(v0.z * inv); t[3] = (__bf16)(v0.w * inv);
            t[4] = (__bf16)(v1.x * inv); t[5] = (__bf16)(v1.y * inv);
            t[6] = (__bf16)(v1.z * inv); t[7] = (__bf16)(v1.w * inv);
            afr[kk] = t;
        } else if (sec == 1) {
            afr[kk] = *(const bf16x8*)(nfb + (size_t)gnA * 64 + koff);
        } else {
            afr[kk] = *(const bf16x8*)(ub + koff);
        }
    }

    float b1v[8];
#pragma unroll
    for (int nt = 0; nt < 8; ++nt) b1v[nt] = b1[nt * 16 + lo];
    float b2v[4];
#pragma unroll
    for (int nt = 0; nt < 4; ++nt) b2v[nt] = b2[nt * 16 + lo];

    // ---- stage W1n (48 chunks) + W2 (16 chunks), once
    for (int c = w; c < 48; c += 8)
        gload16(w1f + c * 64 + l, lds + c * 1024);
    for (int c = w; c < 16; c += 8)
        gload16(w2f + c * 64 + l, lds + 49152 + c * 1024);
    __syncthreads();

    // ---- layer 1: kk = 0..5
    f32x4 acc1[8] = {};
#pragma unroll
    for (int kk = 0; kk < 6; ++kk)
#pragma unroll
        for (int nt = 0; nt < 8; ++nt) {
            bf16x8 bfr = *(const bf16x8*)(lds + ((kk * 8 + nt) * 64 + l) * 16);
            acc1[nt] = __builtin_amdgcn_mfma_f32_16x16x32_bf16(afr[kk], bfr, acc1[nt], 0, 0, 0);
        }
    __syncthreads();   // all W1 reads done; [0,32K) reusable for h

    char* hp = lds + w * 4096;
#pragma unroll
    for (int nt = 0; nt < 8; ++nt) {
        int col = nt * 16 + lo;
#pragma unroll
        for (int r = 0; r < 4; ++r) {
            int row = hi * 4 + r;
            float hv = fmaxf(acc1[nt][r] + b1v[nt], 0.0f);
            *(__bf16*)(hp + SWZ(row, row * 256 + col * 2)) = (__bf16)hv;
        }
    }

    f32x4 acc2[4] = {};
#pragma unroll
    for (int kk = 0; kk < 4; ++kk) {
        int kb = (kk * 32 + hi * 8) * 2;
        bf16x8 a0 = *(const bf16x8*)(hp + SWZ(lo, lo * 256 + kb));
#pragma unroll
        for (int nt = 0; nt < 4; ++nt) {
            bf16x8 bfr = *(const bf16x8*)(lds + 49152 + ((kk * 4 + nt) * 64 + l) * 16);
            acc2[nt] = __builtin_amdgcn_mfma_f32_16x16x32_bf16(a0, bfr, acc2[nt], 0, 0, 0);
        }
    }

    float vsum[4] = {0.f, 0.f, 0.f, 0.f};
#pragma unroll
    for (int r = 0; r < 4; ++r) {
        long gn = nb + hi * 4 + r;
        if (gn >= N) continue;
        int gni = (int)gn;
#pragma unroll
        for (int nt = 0; nt < 4; ++nt) {
            int col = nt * 16 + lo;
            float msg = acc2[nt][r] + b2v[nt];
            out_n[(size_t)gni * 64 + col] = msg + nf[(size_t)gni * 64 + col];
            vsum[nt] += msg;
        }
    }
#pragma unroll
    for (int nt = 0; nt < 4; ++nt) {
        float v = vsum[nt];
        v += __shfl_xor(v, 16);
        v += __shfl_xor(v, 32);
        if (l < 16) nsum_part[((size_t)blockIdx.x * 8 + w) * 64 + nt * 16 + l] = v;
    }
}

// ---------------------------------------------------------------------------
// reduce_two: blocks [0,NBA) sum agg rows -> edge_sum;
//             blocks [NBA,NBA+NBB) sum nsum_part rows -> node_sum.
// ---------------------------------------------------------------------------
__global__ __launch_bounds__(256) void reduce_two(
    const float* __restrict__ aggIn, float* __restrict__ edge_sum, int RA, int NBA,
    const float* __restrict__ nsumIn, float* __restrict__ node_sum, int RB, int NBB)
{
    const float* in; float* out; int R, rb, nb;
    if ((int)blockIdx.x < NBA) { in = aggIn;  out = edge_sum; R = RA; rb = blockIdx.x;       nb = NBA; }
    else                       { in = nsumIn; out = node_sum; R = RB; rb = blockIdx.x - NBA; nb = NBB; }
    int col = threadIdx.x & 63;
    float s = 0.f;
    for (int r = rb * 4 + (threadIdx.x >> 6); r < R; r += nb * 4)
        s += in[(size_t)r * 64 + col];
    __shared__ float sm[256];
    sm[threadIdx.x] = s;
    __syncthreads();
    if (threadIdx.x < 64) {
        float v = sm[threadIdx.x] + sm[threadIdx.x + 64] + sm[threadIdx.x + 128] + sm[threadIdx.x + 192];
        atomicAdd(&out[threadIdx.x], v);
    }
}

// ---------------------------------------------------------------------------
// Global MLP: single block.
// ---------------------------------------------------------------------------
__global__ __launch_bounds__(128) void global_kernel(
    const float* __restrict__ u,
    const float* __restrict__ W1, const float* __restrict__ b1,
    const float* __restrict__ W2, const float* __restrict__ b2,
    const float* __restrict__ node_sum, const float* __restrict__ edge_sum,
    float* __restrict__ out_u, int N, int E)
{
    __shared__ float gm[192];
    __shared__ float h[128];
    int tid = threadIdx.x;
    if (tid < 64) {
        gm[tid]       = node_sum[tid] / (float)N;
        gm[64 + tid]  = edge_sum[tid] / (float)E;
        gm[128 + tid] = u[tid];
    }
    __syncthreads();
    float a = b1[tid];
    for (int k = 0; k < 192; ++k) a = fmaf(gm[k], W1[k * 128 + tid], a);
    h[tid] = fmaxf(a, 0.f);
    __syncthreads();
    if (tid < 64) {
        float o = b2[tid];
        for (int k = 0; k < 128; ++k) o = fmaf(h[k], W2[k * 64 + tid], o);
        out_u[tid] = o + u[tid];
    }
}

extern "C" void kernel_launch(void* const* d_in, const int* in_sizes, int n_in,
                              void* d_out, int out_size, void* d_ws, size_t ws_size,
                              hipStream_t stream) {
    const float* nf  = (const float*)d_in[0];
    const float* ef  = (const float*)d_in[1];
    const float* u   = (const float*)d_in[2];
    const float* eW1 = (const float*)d_in[3];
    const float* eb1 = (const float*)d_in[4];
    const float* eW2 = (const float*)d_in[5];
    const float* eb2 = (const float*)d_in[6];
    const float* nW1 = (const float*)d_in[7];
    const float* nb1 = (const float*)d_in[8];
    const float* nW2 = (const float*)d_in[9];
    const float* nb2 = (const float*)d_in[10];
    const float* gW1 = (const float*)d_in[11];
    const float* gb1 = (const float*)d_in[12];
    const float* gW2 = (const float*)d_in[13];
    const float* gb2 = (const float*)d_in[14];
    const int*   src = (const int*)d_in[15];
    const int*   dst = (const int*)d_in[16];

    const int N = in_sizes[0] / 64;
    const int E = in_sizes[1] / 64;
    const int EDGE_BLOCKS = (E + 127) / 128;
    const int NODE_BLOCKS = (N + 127) / 128;
    const int SCAN_NB = (N + 255) / 256;       // <= 256 for N <= 65536

    char* ws = (char*)d_ws;
    size_t off_b = 0;
    auto alloc = [&](size_t bytes) { size_t c = off_b; off_b += (bytes + 255) & ~(size_t)255; return c; };

    // zeroed region first: degi | cursor | edge_sum | node_sum | agg
    int*    degi     = (int*)(ws + alloc((size_t)N * 4));
    int*    cursor   = (int*)(ws + alloc((size_t)N * 4));
    float*  edge_sum = (float*)(ws + alloc(256));
    float*  node_sum = (float*)(ws + alloc(256));
    float*  agg      = (float*)(ws + alloc((size_t)N * 64 * 4));
    size_t  zero_bytes = off_b;
    int*    offs     = (int*)(ws + alloc((size_t)N * 4));
    int*    bsum     = (int*)(ws + alloc((size_t)SCAN_NB * 4));
    int*    bofs     = (int*)(ws + alloc((size_t)SCAN_NB * 4));
    int*    eidx     = (int*)(ws + alloc((size_t)E * 4));
    float*  nsum_part= (float*)(ws + alloc((size_t)NODE_BLOCKS * 8 * 64 * 4));
    __bf16* nfb   = (__bf16*)(ws + alloc((size_t)N * 64 * 2));
    __bf16* ub    = (__bf16*)(ws + alloc(256));
    __bf16* w1e_f = (__bf16*)(ws + alloc(32768 * 2));
    __bf16* w2e_f = (__bf16*)(ws + alloc(8192 * 2));
    __bf16* w1n_f = (__bf16*)(ws + alloc(24576 * 2));
    __bf16* w2n_f = (__bf16*)(ws + alloc(8192 * 2));

    float* out_n = (float*)d_out;
    float* out_e = out_n + (size_t)N * 64;
    float* out_u = out_e + (size_t)E * 64;

    const int B_FILL = (E + 255) / 256;
    const int B_NF   = (N * 16 + 255) / 256;   // N*64/4 threads
    const int B_W    = (73792 + 255) / 256;

    hipMemsetAsync(d_ws, 0, zero_bytes, stream);
    hist_kernel<<<(E + 255) / 256, 256, 0, stream>>>(dst, degi, E);
    scan_local<<<SCAN_NB, 256, 0, stream>>>(degi, offs, bsum, N);
    scan_blocks<<<1, 256, 0, stream>>>(bsum, bofs, SCAN_NB);
    fill_prep<<<B_FILL + B_NF + B_W, 256, 0, stream>>>(
        dst, offs, bofs, cursor, eidx, E,
        nf, nfb, N * 64, eW1, eW2, nW1, nW2, u,
        w1e_f, w2e_f, w1n_f, w2n_f, ub, B_FILL, B_NF);
    edge_mfma<<<EDGE_BLOCKS, 512, 0, stream>>>(
        ef, nfb, ub, (const bf16x8*)w1e_f, (const bf16x8*)w2e_f, eb1, eb2,
        src, dst, eidx, out_e, agg, E);
    node_mfma<<<NODE_BLOCKS, 512, 0, stream>>>(
        nf, nfb, ub, agg, degi, (const bf16x8*)w1n_f, (const bf16x8*)w2n_f,
        nb1, nb2, out_n, nsum_part, N);
    reduce_two<<<128 + 16, 256, 0, stream>>>(
        agg, edge_sum, N, 128, nsum_part, node_sum, NODE_BLOCKS * 8, 16);
    global_kernel<<<1, 128, 0, stream>>>(
        u, gW1, gb1, gW2, gb2, node_sum, edge_sum, out_u, N, E);
}